// Round 20
// baseline (303.654 us; speedup 1.0000x reference)
//
#include <hip/hip_runtime.h>
#include <stdint.h>

#define D      512
#define NSTEP  128          // SRC steps == decoder steps (TGT-1)
#define EVOC   50000
#define VTILE  128
#define VT2    256                             // logits col-tile
#define NBV2   ((EVOC + VT2 - 1) / VT2)        // 196 logits blocks (single round)
#define LDA_W  36           // A LDS row stride in u32 words (144 B, 16B-aligned)
#define LDB_W  132          // B LDS kw-row stride in u32 words (16B-aligned)
#define LDB2_W 260          // logits B stride: 256 cols + 4 pad (16B-aligned)
#define WM8    (D / 8)                         // 64 Wm-quant helper blocks
#define WO8    ((EVOC + 7) / 8)                // 6250 Wo-quant helper blocks

typedef unsigned int u32x4 __attribute__((ext_vector_type(4)));

// ---- int8 dot4 (v_dot4_i32_i8) ----
__device__ inline int sdot4(int a, int b, int c) {
#if __has_builtin(__builtin_amdgcn_sdot4)
    return __builtin_amdgcn_sdot4(a, b, c, false);
#else
    int r = c;
    r += (int)(int8_t)(a)       * (int)(int8_t)(b);
    r += (int)(int8_t)(a >> 8)  * (int)(int8_t)(b >> 8);
    r += (int)(int8_t)(a >> 16) * (int)(int8_t)(b >> 16);
    r += (int)(int8_t)(a >> 24) * (int)(int8_t)(b >> 24);
    return r;
#endif
}

// ---- int4 dot8 (v_dot8_i32_i4): 8 signed-nibble MACs per instruction ----
__device__ inline int sdot8(uint32_t a, uint32_t b, int c) {
#if __has_builtin(__builtin_amdgcn_sdot8)
    return __builtin_amdgcn_sdot8((int)a, (int)b, c, false);
#else
    int r = c;
    #pragma unroll
    for (int k = 0; k < 8; k++) {
        int av = ((int)(a << (28 - 4 * k))) >> 28;
        int bv = ((int)(b << (28 - 4 * k))) >> 28;
        r += av * bv;
    }
    return r;
#endif
}

__device__ inline int rdlane(uint32_t v, int k) {
#if __has_builtin(__builtin_amdgcn_readlane)
    return (int)__builtin_amdgcn_readlane(v, k);
#else
    return (int)__shfl((int)v, k, 64);
#endif
}

__device__ inline uint32_t pack4(float a, float b, float c, float d, float inv) {
    return  ((uint32_t)(uint8_t)(int8_t)__float2int_rn(a * inv)) |
            ((uint32_t)(uint8_t)(int8_t)__float2int_rn(b * inv) << 8) |
            ((uint32_t)(uint8_t)(int8_t)__float2int_rn(c * inv) << 16) |
            ((uint32_t)(uint8_t)(int8_t)__float2int_rn(d * inv) << 24);
}

__device__ inline float amax4(float4 v) {
    return fmaxf(fmaxf(fabsf(v.x), fabsf(v.y)), fmaxf(fabsf(v.z), fabsf(v.w)));
}

// ---- K_PREP2: Whh INT4 quant (full-row chunked layout) + pre matvec ----
__global__ __launch_bounds__(256) void k_prep2(
        const float* __restrict__ We,   const float* __restrict__ Wd,
        const int* __restrict__ fnums,  const int* __restrict__ enums,
        const float* __restrict__ emb_f,const float* __restrict__ emb_d,
        const float* __restrict__ Wih_e,const float* __restrict__ Wih_d,
        const float* __restrict__ b_e,  const float* __restrict__ b_d,
        uint32_t* __restrict__ q4, float* __restrict__ qsc,
        float* __restrict__ pre_e, float* __restrict__ pre_d) {
    __shared__ float xl[D];
    int bid = blockIdx.x, t = threadIdx.x;
    if (bid < 256) {                       // --- Whh int4 quant, 4 rows/block ---
        int rg = bid * 4 + (t >> 6);       // 0..1023
        int which = rg >> 9, row = rg & 511;
        int lane = t & 63;                 // word index: cols 8*lane..8*lane+7
        const float* W = which ? Wd : We;
        const float* src = W + (size_t)row * D + lane * 8;
        float w[8];
        #pragma unroll
        for (int k = 0; k < 8; k++) w[k] = src[k];
        float m = 0.f;
        #pragma unroll
        for (int k = 0; k < 8; k++) m = fmaxf(m, fabsf(w[k]));
        for (int off = 32; off; off >>= 1) m = fmaxf(m, __shfl_xor(m, off));
        float inv = (m > 0.f) ? 7.f / m : 0.f;
        uint32_t word = 0;
        #pragma unroll
        for (int k = 0; k < 8; k++) {
            int q = max(-7, min(7, __float2int_rn(w[k] * inv)));
            word |= ((uint32_t)(q & 0xF)) << (4 * k);
        }
        q4[((size_t)which * 8192 + (size_t)(lane >> 2) * 512 + row) * 4 + (lane & 3)] = word;
        if (lane == 0) qsc[which * D + row] = m / 7.f;
    } else {                               // --- pre matvec (256 blocks) ---
        int bb = bid - 256;
        int kind = bb >> 7, s = bb & 127;
        const float* emb = kind ? emb_d : emb_f;
        int idx          = kind ? enums[s] : fnums[s];
        const float* W   = kind ? Wih_d : Wih_e;
        const float* b   = kind ? b_d : b_e;
        float* pre       = kind ? pre_d : pre_e;
        xl[t]       = emb[(size_t)idx * D + t];
        xl[t + 256] = emb[(size_t)idx * D + t + 256];
        __syncthreads();
        for (int rep = 0; rep < 2; rep++) {
            int o = t + rep * 256;
            float acc = b[o];
            const float4* Wr = (const float4*)(W + (size_t)o * D);
            #pragma unroll 8
            for (int k4 = 0; k4 < D / 4; k4++) {
                float4 w = Wr[k4];
                acc += w.x * xl[4*k4] + w.y * xl[4*k4+1] + w.z * xl[4*k4+2] + w.w * xl[4*k4+3];
            }
            pre[(size_t)s * D + o] = acc;
        }
    }
}

// ---- K2 (fused, 512 threads): blocks 0-1 = scans (structural floor ~109us:
// 128 KB/step weights through LDS @ ~85 B/cyc + serial tail); blocks 2+ =
// Wm/Wo quant on otherwise-idle CUs. ----
__global__ __launch_bounds__(512)
__attribute__((amdgpu_waves_per_eu(4, 4)))
void k_scan_fused(
        const uint32_t* __restrict__ q4, const float* __restrict__ qsc,
        const float* __restrict__ pre_e, const float* __restrict__ pre_d,
        const float* __restrict__ h0_e, const float* __restrict__ h0_d,
        float* __restrict__ fencs, float* __restrict__ h2s,
        const float* __restrict__ Wm, const float* __restrict__ Wo,
        int8_t* __restrict__ wmq, float* __restrict__ wmsc,
        uint32_t* __restrict__ woq2, float* __restrict__ wosc) {
    __shared__ __align__(16) uint32_t wlds[32768];  // 128 KB: ALL 16 chunks
    __shared__ __align__(4) uint32_t hq4[2][64];    // int4 h, double-buffered
    int bid = blockIdx.x, t = threadIdx.x;

    if (bid >= 2) {
        int lane = t & 63, sub = t >> 6;           // 8 rows/block, 64 lanes/row
        if (bid < 2 + WM8) {                       // --- Wm int8 quant ---
            int row = (bid - 2) * 8 + sub;         // 0..511
            const float4* src = (const float4*)(Wm + (size_t)row * 2 * D);
            float4 a = src[lane], b = src[lane + 64], c = src[lane + 128], d2 = src[lane + 192];
            float m = fmaxf(fmaxf(amax4(a), amax4(b)), fmaxf(amax4(c), amax4(d2)));
            for (int off = 32; off; off >>= 1) m = fmaxf(m, __shfl_xor(m, off));
            float inv = (m > 0.f) ? 127.f / m : 0.f;
            uint32_t* dst = (uint32_t*)(wmq + (size_t)row * 2 * D);
            dst[lane]       = pack4(a.x, a.y, a.z, a.w, inv);
            dst[lane + 64]  = pack4(b.x, b.y, b.z, b.w, inv);
            dst[lane + 128] = pack4(c.x, c.y, c.z, c.w, inv);
            dst[lane + 192] = pack4(d2.x, d2.y, d2.z, d2.w, inv);
            if (lane == 0) wmsc[row] = m / 127.f;
        } else {                                   // --- Wo int8 quant -> woq2 ---
            int row = (bid - 2 - WM8) * 8 + sub;
            if (row < EVOC) {
                const float4* src = (const float4*)(Wo + (size_t)row * D);
                float4 v0 = src[lane], v1 = src[lane + 64];
                float m = fmaxf(amax4(v0), amax4(v1));
                for (int off = 32; off; off >>= 1) m = fmaxf(m, __shfl_xor(m, off));
                float inv = (m > 0.f) ? 127.f / m : 0.f;
                uint32_t w1 = pack4(v0.x, v0.y, v0.z, v0.w, inv);
                uint32_t w2 = pack4(v1.x, v1.y, v1.z, v1.w, inv);
                int wA = lane, wB = lane + 64;
                woq2[((size_t)(row >> 7) * 4 + (wA >> 5)) * 4096 + (size_t)(row & 127) * 32 + (wA & 31)] = w1;
                woq2[((size_t)(row >> 7) * 4 + (wB >> 5)) * 4096 + (size_t)(row & 127) * 32 + (wB & 31)] = w2;
                if (lane == 0) wosc[row] = m / 127.f;
            }
        }
        return;
    }

    // ---- scan path (blocks 0,1), 512 threads, r = t ----
    int lane = t & 63;
    int r = t;
    int which = bid;
    const float* pre = which ? pre_d : pre_e;
    const float* h0  = which ? h0_d : h0_e;
    float*       hs  = which ? h2s : fencs;
    float sw = qsc[which * D + r] * (1.f / 7.f);   // (wmax/7) * (1/7)
    const u32x4* wq = (const u32x4*)q4 + (size_t)which * 8192 + t;   // chunk c at wq[c*512]

    // one-time: stage ALL 16 weight chunks into LDS (128 KB)
    u32x4* wl = (u32x4*)wlds;
    #pragma unroll
    for (int c = 0; c < 16; c++) wl[c * 512 + t] = wq[c * 512];

    {   // init h0 -> int4 nibbles (all 512 lanes, rows paired via shfl)
        float h0v = fminf(fmaxf(h0[r], -0.999f), 0.999f);
        int nib = max(-7, min(7, __float2int_rn(h0v * 7.f)));
        uint32_t mynib = (uint32_t)(nib & 0xF);
        uint32_t other = (uint32_t)__shfl_xor((int)mynib, 1);
        if (!(r & 1))
            ((uint8_t*)&hq4[0][0])[r >> 1] = (uint8_t)(mynib | (other << 4));
    }
    __syncthreads();

    int p = 0;
    for (int step = 0; step < NSTEP; step++) {
        uint32_t own = hq4[p][lane];               // wave holds all 64 h words
        int a0 = 0, a1 = 0, a2 = 0, a3 = 0;
        #define DOTC(c) { u32x4 wv = wl[(c) * 512 + t];                 \
            a0 = sdot8(wv.x, (uint32_t)rdlane(own, (c) * 4 + 0), a0);   \
            a1 = sdot8(wv.y, (uint32_t)rdlane(own, (c) * 4 + 1), a1);   \
            a2 = sdot8(wv.z, (uint32_t)rdlane(own, (c) * 4 + 2), a2);   \
            a3 = sdot8(wv.w, (uint32_t)rdlane(own, (c) * 4 + 3), a3); }
        DOTC(0)  DOTC(1)  DOTC(2)  DOTC(3)
        DOTC(4)  DOTC(5)  DOTC(6)  DOTC(7)
        DOTC(8)  DOTC(9)  DOTC(10) DOTC(11)
        DOTC(12) DOTC(13) DOTC(14) DOTC(15)
        #undef DOTC
        int acc = (a0 + a1) + (a2 + a3);
        float h2 = tanhf(pre[(size_t)step * D + r] + (float)acc * sw);
        hs[(size_t)step * D + r] = h2;
        int nib = max(-7, min(7, __float2int_rn(h2 * 7.f)));
        uint32_t mynib = (uint32_t)(nib & 0xF);
        uint32_t other = (uint32_t)__shfl_xor((int)mynib, 1);
        if (!(r & 1))
            ((uint8_t*)&hq4[p ^ 1][0])[r >> 1] = (uint8_t)(mynib | (other << 4));
        __syncthreads();                            // ONE barrier per step
        p ^= 1;
    }
}

// ---- K3a: attention scores + softmax + context -> chq = int8 [c | h2] ----
__global__ __launch_bounds__(512) void k_att1(
        const float* __restrict__ fencs, const float* __restrict__ h2s,
        int8_t* __restrict__ chq) {
    __shared__ float h2l[D], sc[NSTEP], red[64];
    __shared__ float ftile[32 * D];
    int s = blockIdx.x, t = threadIdx.x;
    h2l[t] = h2s[(size_t)s * D + t];
    __syncthreads();

    {   // scores[j] = fencs[j] . h2 ; thread (j = t>>2, q = t&3)
        int j = t >> 2, q = t & 3;
        const float4* fr = (const float4*)(fencs + (size_t)j * D + q * 128);
        const float4* hr = (const float4*)(h2l + q * 128);
        float acc = 0.f;
        #pragma unroll 8
        for (int k4 = 0; k4 < 32; k4++) {
            float4 f = fr[k4], hh = hr[k4];
            acc += f.x*hh.x + f.y*hh.y + f.z*hh.z + f.w*hh.w;
        }
        acc += __shfl_xor(acc, 1);
        acc += __shfl_xor(acc, 2);
        if (q == 0) sc[j] = acc;
    }
    __syncthreads();
    if (t < 64) {
        float m = fmaxf(sc[t], sc[t + 64]);
        for (int off = 32; off; off >>= 1) m = fmaxf(m, __shfl_xor(m, off));
        if (t == 0) red[0] = m;
    }
    __syncthreads();
    float mx = red[0];
    __syncthreads();
    if (t < NSTEP) sc[t] = expf(sc[t] - mx);
    __syncthreads();
    if (t < 64) {
        float v = sc[t] + sc[t + 64];
        for (int off = 32; off; off >>= 1) v += __shfl_xor(v, off);
        if (t == 0) red[0] = v;
    }
    __syncthreads();
    float inv = 1.0f / red[0];

    float cacc = 0.f;
    for (int jt = 0; jt < 4; jt++) {
        #pragma unroll
        for (int k = 0; k < 32; k++)
            ftile[t + k * D] = fencs[(size_t)jt * 32 * D + t + k * D];
        __syncthreads();
        #pragma unroll 8
        for (int j = 0; j < 32; j++)
            cacc += sc[jt * 32 + j] * ftile[j * D + t];
        __syncthreads();
    }
    float cv = cacc * inv;
    chq[(size_t)s * 2 * D + t]     = (int8_t)__float2int_rn(cv * 127.f);
    chq[(size_t)s * 2 * D + D + t] = (int8_t)__float2int_rn(h2l[t] * 127.f);
}

// ---- K3b: m = tanh([c,h2] @ Wm^T + bm) as int8 GEMM, 16 blocks ----
__global__ __launch_bounds__(512) void k_att2(
        const int8_t* __restrict__ chq, const int8_t* __restrict__ wmq,
        const float* __restrict__ wmsc, const float* __restrict__ bm,
        int8_t* __restrict__ mq) {
    __shared__ __align__(16) uint32_t a_s[32 * LDA_W];
    __shared__ __align__(16) uint32_t b_s[32 * LDB_W];
    int t = threadIdx.x;
    int v0 = (blockIdx.x & 3) * VTILE;      // col tile
    int r0 = (blockIdx.x >> 2) * 32;        // row tile
    int ti = t >> 5, tj = t & 31;           // ti -> rows r0+2ti..+1 ; tj -> cols v0+4tj..
    int lrow = t >> 3, lq = t & 7;
    int acc[2][4] = {};

    for (int kc = 0; kc < 8; kc++) {        // K = 1024 -> 8 chunks of 128
        if (t < 256) {                      // A: 32 rows x 8 quads
            int row = t >> 3, q = t & 7;
            uint4 av = *(const uint4*)(chq + (size_t)(r0 + row) * 2 * D + kc * 128 + q * 16);
            *(uint4*)&a_s[row * LDA_W + q * 4] = av;
        }
        #pragma unroll
        for (int rep = 0; rep < 2; rep++) { // B: 128 cols x 8 quads
            int row = lrow + rep * 64;
            int v = v0 + row;
            uint4 bv = *(const uint4*)(wmq + (size_t)v * 2 * D + kc * 128 + lq * 16);
            b_s[(lq*4+0) * LDB_W + row] = bv.x;
            b_s[(lq*4+1) * LDB_W + row] = bv.y;
            b_s[(lq*4+2) * LDB_W + row] = bv.z;
            b_s[(lq*4+3) * LDB_W + row] = bv.w;
        }
        __syncthreads();
        #pragma unroll
        for (int q = 0; q < 8; q++) {
            uint4 aw0 = *(const uint4*)&a_s[(ti*2 + 0) * LDA_W + q*4];
            uint4 aw1 = *(const uint4*)&a_s[(ti*2 + 1) * LDA_W + q*4];
            #pragma unroll
            for (int k4 = 0; k4 < 4; k4++) {
                uint4 bw = *(const uint4*)&b_s[(q*4 + k4) * LDB_W + tj * 4];
                uint32_t a0 = (k4 == 0) ? aw0.x : (k4 == 1) ? aw0.y
                            : (k4 == 2) ? aw0.z : aw0.w;
                uint32_t a1 = (k4 == 0) ? aw1.x : (k4 == 1) ? aw1.y
                            : (k4 == 2) ? aw1.z : aw1.w;
                acc[0][0] = sdot4((int)a0, (int)bw.x, acc[0][0]);
                acc[0][1] = sdot4((int)a0, (int)bw.y, acc[0][1]);
                acc[0][2] = sdot4((int)a0, (int)bw.z, acc[0][2]);
                acc[0][3] = sdot4((int)a0, (int)bw.w, acc[0][3]);
                acc[1][0] = sdot4((int)a1, (int)bw.x, acc[1][0]);
                acc[1][1] = sdot4((int)a1, (int)bw.y, acc[1][1]);
                acc[1][2] = sdot4((int)a1, (int)bw.z, acc[1][2]);
                acc[1][3] = sdot4((int)a1, (int)bw.w, acc[1][3]);
            }
        }
        __syncthreads();
    }

    float sw4[4], bm4[4];
    #pragma unroll
    for (int jj = 0; jj < 4; jj++) {
        int col = v0 + tj * 4 + jj;
        sw4[jj] = wmsc[col] * (1.f / (127.f * 127.f));
        bm4[jj] = bm[col];
    }
    #pragma unroll
    for (int i = 0; i < 2; i++) {
        int s = r0 + ti * 2 + i;
        float m0 = tanhf((float)acc[i][0] * sw4[0] + bm4[0]);
        float m1 = tanhf((float)acc[i][1] * sw4[1] + bm4[1]);
        float m2 = tanhf((float)acc[i][2] * sw4[2] + bm4[2]);
        float m3 = tanhf((float)acc[i][3] * sw4[3] + bm4[3]);
        ((uint32_t*)mq)[(size_t)s * (D / 4) + (v0 >> 2) + tj] = pack4(m0, m1, m2, m3, 127.f);
    }
}

// ---- K4: int8 logits GEMM, 128 x 256 tile (196 blocks = ONE block-round),
// 8x8 outputs/thread (33% fewer LDS reads per dot than 8x4) ----
__global__ __launch_bounds__(512)
__attribute__((amdgpu_waves_per_eu(2, 2)))
void k_logits(
        const int8_t* __restrict__ mq, const uint32_t* __restrict__ woq2,
        const float* __restrict__ wosc, const float* __restrict__ bo,
        const int* __restrict__ enums,
        float* __restrict__ pmax, float* __restrict__ psum, float* __restrict__ pick) {
    __shared__ __align__(16) uint32_t a_s[128 * LDA_W];   // 18.4 KB
    __shared__ __align__(16) uint32_t b_s[32 * LDB2_W];   // 33.3 KB
    int b = blockIdx.x, t = threadIdx.x;
    int v0 = b * VT2;
    int ti = t >> 5, tj = t & 31;           // rows ti*8+i, cols v0 + tj*8 + jj
    int lrow = t >> 3, lq = t & 7;
    int acc[8][8] = {};

    for (int kc = 0; kc < 4; kc++) {
        #pragma unroll
        for (int rep = 0; rep < 2; rep++) {   // A: 128 rows x 8 quads
            int row = lrow + rep * 64;
            uint4 av = *(const uint4*)(mq + (size_t)row * D + kc * 128 + lq * 16);
            *(uint4*)&a_s[row * LDA_W + lq * 4] = av;
        }
        #pragma unroll
        for (int H = 0; H < 2; H++) {         // B: two 128-col groups
            const uint4* bsrc = (const uint4*)(woq2 + ((size_t)(2*b + H) * 4 + kc) * 4096);
            #pragma unroll
            for (int rep = 0; rep < 2; rep++) {
                int j = t + rep * 512;
                uint4 bv = bsrc[j];
                int col = H * 128 + (j >> 3), q = j & 7;
                b_s[(q*4+0) * LDB2_W + col] = bv.x;
                b_s[(q*4+1) * LDB2_W + col] = bv.y;
                b_s[(q*4+2) * LDB2_W + col] = bv.z;
                b_s[(q*4+3) * LDB2_W + col] = bv.w;
            }
        }
        __syncthreads();
        #pragma unroll
        for (int q = 0; q < 8; q++) {
            uint4 aw[8];
            #pragma unroll
            for (int i = 0; i < 8; i++)
                aw[i] = *(const uint4*)&a_s[(ti*8 + i) * LDA_W + q*4];
            #pragma unroll
            for (int k4 = 0; k4 < 4; k4++) {
                uint4 bw0 = *(const uint4*)&b_s[(q*4 + k4) * LDB2_W + tj * 8];
                uint4 bw1 = *(const uint4*)&b_s[(q*4 + k4) * LDB2_W + tj * 8 + 4];
                #pragma unroll
                for (int i = 0; i < 8; i++) {
                    uint32_t a = (k4 == 0) ? aw[i].x : (k4 == 1) ? aw[i].y
                               : (k4 == 2) ? aw[i].z : aw[i].w;
                    acc[i][0] = sdot4((int)a, (int)bw0.x, acc[i][0]);
                    acc[i][1] = sdot4((int)a, (int)bw0.y, acc[i][1]);
                    acc[i][2] = sdot4((int)a, (int)bw0.z, acc[i][2]);
                    acc[i][3] = sdot4((int)a, (int)bw0.w, acc[i][3]);
                    acc[i][4] = sdot4((int)a, (int)bw1.x, acc[i][4]);
                    acc[i][5] = sdot4((int)a, (int)bw1.y, acc[i][5]);
                    acc[i][6] = sdot4((int)a, (int)bw1.z, acc[i][6]);
                    acc[i][7] = sdot4((int)a, (int)bw1.w, acc[i][7]);
                }
            }
        }
        __syncthreads();
    }

    float sw8[8], bo8[8];
    int vld[8];
    #pragma unroll
    for (int jj = 0; jj < 8; jj++) {
        int v = v0 + tj * 8 + jj;
        vld[jj] = (v < EVOC);
        sw8[jj] = vld[jj] ? wosc[v] * (1.f / 127.f) : 0.f;
        bo8[jj] = vld[jj] ? bo[v] : 0.f;
    }
    #pragma unroll
    for (int i = 0; i < 8; i++) {
        int s = ti * 8 + i;
        float l[8];
        float mx = -1e30f;
        #pragma unroll
        for (int jj = 0; jj < 8; jj++) {
            l[jj] = vld[jj] ? (float)acc[i][jj] * sw8[jj] + bo8[jj] : -1e30f;
            mx = fmaxf(mx, l[jj]);
        }
        #pragma unroll
        for (int off = 1; off < 32; off <<= 1) mx = fmaxf(mx, __shfl_xor(mx, off));
        float sm = 0.f;
        #pragma unroll
        for (int jj = 0; jj < 8; jj++)
            if (vld[jj]) sm += expf(l[jj] - mx);
        #pragma unroll
        for (int off = 1; off < 32; off <<= 1) sm += __shfl_xor(sm, off);
        if (tj == 0) { pmax[b * NSTEP + s] = mx; psum[b * NSTEP + s] = sm; }
        int tgt = enums[s + 1];
        if (tgt >= v0 && tgt < v0 + VT2) {
            int c = tgt - v0;
            if ((c >> 3) == tj) pick[s] = l[c & 7];
        }
    }
}

// ---- K5a: per-step logsumexp combine, 128 blocks in parallel ----
__global__ __launch_bounds__(256) void k_final_par(
        const float* __restrict__ pmax, const float* __restrict__ psum,
        const float* __restrict__ pick, float* __restrict__ lp) {
    __shared__ float red[8];
    int s = blockIdx.x, t = threadIdx.x;
    float M = -1e30f;
    for (int b = t; b < NBV2; b += 256) M = fmaxf(M, pmax[b * NSTEP + s]);
    for (int off = 32; off; off >>= 1) M = fmaxf(M, __shfl_xor(M, off));
    if ((t & 63) == 0) red[t >> 6] = M;
    __syncthreads();
    M = fmaxf(fmaxf(red[0], red[1]), fmaxf(red[2], red[3]));
    float S = 0.f;
    for (int b = t; b < NBV2; b += 256) S += psum[b * NSTEP + s] * expf(pmax[b * NSTEP + s] - M);
    for (int off = 32; off; off >>= 1) S += __shfl_xor(S, off);
    if ((t & 63) == 0) red[4 + (t >> 6)] = S;
    __syncthreads();
    if (t == 0) {
        S = red[4] + red[5] + red[6] + red[7];
        lp[s] = pick[s] - (M + logf(S));
    }
}

// ---- K5b: sum 128 logprobs ----
__global__ void k_final_sum(const float* __restrict__ lp, float* __restrict__ out) {
    __shared__ float red[NSTEP];
    int t = threadIdx.x;
    red[t] = lp[t];
    __syncthreads();
    for (int off = 64; off > 0; off >>= 1) {
        if (t < off) red[t] += red[t + off];
        __syncthreads();
    }
    if (t == 0) out[0] = red[0];
}

extern "C" void kernel_launch(void* const* d_in, const int* in_sizes, int n_in,
                              void* d_out, int out_size, void* d_ws, size_t ws_size,
                              hipStream_t stream) {
    const int*   fnums = (const int*)  d_in[0];
    const int*   enums = (const int*)  d_in[1];
    const float* emb_f = (const float*)d_in[2];
    const float* Wih_e = (const float*)d_in[3];
    const float* Whh_e = (const float*)d_in[4];
    const float* b_e   = (const float*)d_in[5];
    const float* h0_e  = (const float*)d_in[6];
    const float* emb_d = (const float*)d_in[7];
    const float* Wih_d = (const float*)d_in[8];
    const float* Whh_d = (const float*)d_in[9];
    const float* b_d   = (const float*)d_in[10];
    const float* h0_d  = (const float*)d_in[11];
    const float* Wm    = (const float*)d_in[12];
    const float* bm    = (const float*)d_in[13];
    const float* Wo    = (const float*)d_in[14];
    const float* bo    = (const float*)d_in[15];

    float* ws = (float*)d_ws;
    float* pre_e = ws;                        // 65536
    float* pre_d = ws + 65536;                // 65536
    float* fencs = ws + 131072;               // 65536
    float* h2s   = ws + 196608;               // 65536
    float* pmax  = ws + 262144;               // 50048
    float* psum  = ws + 312192;               // 50048
    float* pick  = ws + 362240;               // 128
    float* lp    = ws + 362368;               // 128
    float* qsc   = ws + 362496;               // 1024
    float* wmsc  = ws + 363520;               // 512
    float* wosc  = ws + 364032;               // 50048
    uint32_t* q4 = (uint32_t*)(ws + 414080);  // 65536 u32 = 256 KB int4 scan weights
    int8_t*   wmq  = (int8_t*)(ws + 479616);  // 512 KB
    int8_t*   chq  = (int8_t*)(ws + 610688);  // 128 KB
    int8_t*   mq   = (int8_t*)(ws + 643456);  // 64 KB
    uint32_t* woq2 = (uint32_t*)(ws + 659840);// 392 groups x 16384 u32 = 25.7 MB

    k_prep2<<<dim3(512), dim3(256), 0, stream>>>(
        Whh_e, Whh_d, fnums, enums, emb_f, emb_d, Wih_e, Wih_d, b_e, b_d,
        q4, qsc, pre_e, pre_d);
    k_scan_fused<<<dim3(2 + WM8 + WO8), dim3(512), 0, stream>>>(
        q4, qsc, pre_e, pre_d, h0_e, h0_d, fencs, h2s,
        Wm, Wo, wmq, wmsc, woq2, wosc);
    k_att1<<<dim3(NSTEP), dim3(512), 0, stream>>>(fencs, h2s, chq);
    k_att2<<<dim3(16), dim3(512), 0, stream>>>(chq, wmq, wmsc, bm, mq);
    k_logits<<<dim3(NBV2), dim3(512), 0, stream>>>(mq, woq2, wosc, bo, enums, pmax, psum, pick);
    k_final_par<<<dim3(NSTEP), dim3(256), 0, stream>>>(pmax, psum, pick, lp);
    k_final_sum<<<dim3(1), dim3(NSTEP), 0, stream>>>(lp, (float*)d_out);
}

// Round 21
// 224.317 us; speedup vs baseline: 1.3537x; 1.3537x over previous
//
#include <hip/hip_runtime.h>
#include <stdint.h>

#define D      512
#define NSTEP  128          // SRC steps == decoder steps (TGT-1)
#define EVOC   50000
#define VTILE  128
#define NBV    ((EVOC + VTILE - 1) / VTILE)   // 391
#define LDA_W  36           // A LDS row stride in u32 words (144 B, 16B-aligned)
#define LDB_W  132          // B LDS kw-row stride in u32 words (16B-aligned)
#define WM8    (D / 8)                         // 64 Wm-quant helper blocks
#define WO8    ((EVOC + 7) / 8)                // 6250 Wo-quant helper blocks

typedef unsigned int u32x4 __attribute__((ext_vector_type(4)));

// ---- int8 dot4 (v_dot4_i32_i8) ----
__device__ inline int sdot4(int a, int b, int c) {
#if __has_builtin(__builtin_amdgcn_sdot4)
    return __builtin_amdgcn_sdot4(a, b, c, false);
#else
    int r = c;
    r += (int)(int8_t)(a)       * (int)(int8_t)(b);
    r += (int)(int8_t)(a >> 8)  * (int)(int8_t)(b >> 8);
    r += (int)(int8_t)(a >> 16) * (int)(int8_t)(b >> 16);
    r += (int)(int8_t)(a >> 24) * (int)(int8_t)(b >> 24);
    return r;
#endif
}

// ---- int4 dot8 (v_dot8_i32_i4): 8 signed-nibble MACs per instruction ----
__device__ inline int sdot8(uint32_t a, uint32_t b, int c) {
#if __has_builtin(__builtin_amdgcn_sdot8)
    return __builtin_amdgcn_sdot8((int)a, (int)b, c, false);
#else
    int r = c;
    #pragma unroll
    for (int k = 0; k < 8; k++) {
        int av = ((int)(a << (28 - 4 * k))) >> 28;
        int bv = ((int)(b << (28 - 4 * k))) >> 28;
        r += av * bv;
    }
    return r;
#endif
}

__device__ inline int rdlane(uint32_t v, int k) {
#if __has_builtin(__builtin_amdgcn_readlane)
    return (int)__builtin_amdgcn_readlane(v, k);
#else
    return (int)__shfl((int)v, k, 64);
#endif
}

__device__ inline uint32_t pack4(float a, float b, float c, float d, float inv) {
    return  ((uint32_t)(uint8_t)(int8_t)__float2int_rn(a * inv)) |
            ((uint32_t)(uint8_t)(int8_t)__float2int_rn(b * inv) << 8) |
            ((uint32_t)(uint8_t)(int8_t)__float2int_rn(c * inv) << 16) |
            ((uint32_t)(uint8_t)(int8_t)__float2int_rn(d * inv) << 24);
}

__device__ inline float amax4(float4 v) {
    return fmaxf(fmaxf(fabsf(v.x), fabsf(v.y)), fmaxf(fabsf(v.z), fabsf(v.w)));
}

// ---- K_PREP2: Whh INT4 quant (full-row chunked layout) + pre matvec ----
__global__ __launch_bounds__(256) void k_prep2(
        const float* __restrict__ We,   const float* __restrict__ Wd,
        const int* __restrict__ fnums,  const int* __restrict__ enums,
        const float* __restrict__ emb_f,const float* __restrict__ emb_d,
        const float* __restrict__ Wih_e,const float* __restrict__ Wih_d,
        const float* __restrict__ b_e,  const float* __restrict__ b_d,
        uint32_t* __restrict__ q4, float* __restrict__ qsc,
        float* __restrict__ pre_e, float* __restrict__ pre_d) {
    __shared__ float xl[D];
    int bid = blockIdx.x, t = threadIdx.x;
    if (bid < 256) {                       // --- Whh int4 quant, 4 rows/block ---
        int rg = bid * 4 + (t >> 6);       // 0..1023
        int which = rg >> 9, row = rg & 511;
        int lane = t & 63;                 // word index: cols 8*lane..8*lane+7
        const float* W = which ? Wd : We;
        const float* src = W + (size_t)row * D + lane * 8;
        float w[8];
        #pragma unroll
        for (int k = 0; k < 8; k++) w[k] = src[k];
        float m = 0.f;
        #pragma unroll
        for (int k = 0; k < 8; k++) m = fmaxf(m, fabsf(w[k]));
        for (int off = 32; off; off >>= 1) m = fmaxf(m, __shfl_xor(m, off));
        float inv = (m > 0.f) ? 7.f / m : 0.f;
        uint32_t word = 0;
        #pragma unroll
        for (int k = 0; k < 8; k++) {
            int q = max(-7, min(7, __float2int_rn(w[k] * inv)));
            word |= ((uint32_t)(q & 0xF)) << (4 * k);
        }
        q4[((size_t)which * 8192 + (size_t)(lane >> 2) * 512 + row) * 4 + (lane & 3)] = word;
        if (lane == 0) qsc[which * D + row] = m / 7.f;
    } else {                               // --- pre matvec (256 blocks) ---
        int bb = bid - 256;
        int kind = bb >> 7, s = bb & 127;
        const float* emb = kind ? emb_d : emb_f;
        int idx          = kind ? enums[s] : fnums[s];
        const float* W   = kind ? Wih_d : Wih_e;
        const float* b   = kind ? b_d : b_e;
        float* pre       = kind ? pre_d : pre_e;
        xl[t]       = emb[(size_t)idx * D + t];
        xl[t + 256] = emb[(size_t)idx * D + t + 256];
        __syncthreads();
        for (int rep = 0; rep < 2; rep++) {
            int o = t + rep * 256;
            float acc = b[o];
            const float4* Wr = (const float4*)(W + (size_t)o * D);
            #pragma unroll 8
            for (int k4 = 0; k4 < D / 4; k4++) {
                float4 w = Wr[k4];
                acc += w.x * xl[4*k4] + w.y * xl[4*k4+1] + w.z * xl[4*k4+2] + w.w * xl[4*k4+3];
            }
            pre[(size_t)s * D + o] = acc;
        }
    }
}

// ---- K2 (fused, 512 threads): blocks 0-1 = scans (structural floor ~109us);
// blocks 2+ = Wm/Wo quant on otherwise-idle CUs. ----
__global__ __launch_bounds__(512)
__attribute__((amdgpu_waves_per_eu(4, 4)))
void k_scan_fused(
        const uint32_t* __restrict__ q4, const float* __restrict__ qsc,
        const float* __restrict__ pre_e, const float* __restrict__ pre_d,
        const float* __restrict__ h0_e, const float* __restrict__ h0_d,
        float* __restrict__ fencs, float* __restrict__ h2s,
        const float* __restrict__ Wm, const float* __restrict__ Wo,
        int8_t* __restrict__ wmq, float* __restrict__ wmsc,
        uint32_t* __restrict__ woq2, float* __restrict__ wosc) {
    __shared__ __align__(16) uint32_t wlds[32768];  // 128 KB: ALL 16 chunks
    __shared__ __align__(4) uint32_t hq4[2][64];    // int4 h, double-buffered
    int bid = blockIdx.x, t = threadIdx.x;

    if (bid >= 2) {
        int lane = t & 63, sub = t >> 6;           // 8 rows/block, 64 lanes/row
        if (bid < 2 + WM8) {                       // --- Wm int8 quant ---
            int row = (bid - 2) * 8 + sub;         // 0..511
            const float4* src = (const float4*)(Wm + (size_t)row * 2 * D);
            float4 a = src[lane], b = src[lane + 64], c = src[lane + 128], d2 = src[lane + 192];
            float m = fmaxf(fmaxf(amax4(a), amax4(b)), fmaxf(amax4(c), amax4(d2)));
            for (int off = 32; off; off >>= 1) m = fmaxf(m, __shfl_xor(m, off));
            float inv = (m > 0.f) ? 127.f / m : 0.f;
            uint32_t* dst = (uint32_t*)(wmq + (size_t)row * 2 * D);
            dst[lane]       = pack4(a.x, a.y, a.z, a.w, inv);
            dst[lane + 64]  = pack4(b.x, b.y, b.z, b.w, inv);
            dst[lane + 128] = pack4(c.x, c.y, c.z, c.w, inv);
            dst[lane + 192] = pack4(d2.x, d2.y, d2.z, d2.w, inv);
            if (lane == 0) wmsc[row] = m / 127.f;
        } else {                                   // --- Wo int8 quant -> woq2 ---
            int row = (bid - 2 - WM8) * 8 + sub;
            if (row < EVOC) {
                const float4* src = (const float4*)(Wo + (size_t)row * D);
                float4 v0 = src[lane], v1 = src[lane + 64];
                float m = fmaxf(amax4(v0), amax4(v1));
                for (int off = 32; off; off >>= 1) m = fmaxf(m, __shfl_xor(m, off));
                float inv = (m > 0.f) ? 127.f / m : 0.f;
                uint32_t w1 = pack4(v0.x, v0.y, v0.z, v0.w, inv);
                uint32_t w2 = pack4(v1.x, v1.y, v1.z, v1.w, inv);
                int wA = lane, wB = lane + 64;
                woq2[((size_t)(row >> 7) * 4 + (wA >> 5)) * 4096 + (size_t)(row & 127) * 32 + (wA & 31)] = w1;
                woq2[((size_t)(row >> 7) * 4 + (wB >> 5)) * 4096 + (size_t)(row & 127) * 32 + (wB & 31)] = w2;
                if (lane == 0) wosc[row] = m / 127.f;
            }
        }
        return;
    }

    // ---- scan path (blocks 0,1), 512 threads, r = t ----
    int lane = t & 63;
    int r = t;
    int which = bid;
    const float* pre = which ? pre_d : pre_e;
    const float* h0  = which ? h0_d : h0_e;
    float*       hs  = which ? h2s : fencs;
    float sw = qsc[which * D + r] * (1.f / 7.f);   // (wmax/7) * (1/7)
    const u32x4* wq = (const u32x4*)q4 + (size_t)which * 8192 + t;   // chunk c at wq[c*512]

    // one-time: stage ALL 16 weight chunks into LDS (128 KB)
    u32x4* wl = (u32x4*)wlds;
    #pragma unroll
    for (int c = 0; c < 16; c++) wl[c * 512 + t] = wq[c * 512];

    {   // init h0 -> int4 nibbles (all 512 lanes, rows paired via shfl)
        float h0v = fminf(fmaxf(h0[r], -0.999f), 0.999f);
        int nib = max(-7, min(7, __float2int_rn(h0v * 7.f)));
        uint32_t mynib = (uint32_t)(nib & 0xF);
        uint32_t other = (uint32_t)__shfl_xor((int)mynib, 1);
        if (!(r & 1))
            ((uint8_t*)&hq4[0][0])[r >> 1] = (uint8_t)(mynib | (other << 4));
    }
    __syncthreads();

    int p = 0;
    for (int step = 0; step < NSTEP; step++) {
        uint32_t own = hq4[p][lane];               // wave holds all 64 h words
        int a0 = 0, a1 = 0, a2 = 0, a3 = 0;
        #define DOTC(c) { u32x4 wv = wl[(c) * 512 + t];                 \
            a0 = sdot8(wv.x, (uint32_t)rdlane(own, (c) * 4 + 0), a0);   \
            a1 = sdot8(wv.y, (uint32_t)rdlane(own, (c) * 4 + 1), a1);   \
            a2 = sdot8(wv.z, (uint32_t)rdlane(own, (c) * 4 + 2), a2);   \
            a3 = sdot8(wv.w, (uint32_t)rdlane(own, (c) * 4 + 3), a3); }
        DOTC(0)  DOTC(1)  DOTC(2)  DOTC(3)
        DOTC(4)  DOTC(5)  DOTC(6)  DOTC(7)
        DOTC(8)  DOTC(9)  DOTC(10) DOTC(11)
        DOTC(12) DOTC(13) DOTC(14) DOTC(15)
        #undef DOTC
        int acc = (a0 + a1) + (a2 + a3);
        float h2 = tanhf(pre[(size_t)step * D + r] + (float)acc * sw);
        hs[(size_t)step * D + r] = h2;
        int nib = max(-7, min(7, __float2int_rn(h2 * 7.f)));
        uint32_t mynib = (uint32_t)(nib & 0xF);
        uint32_t other = (uint32_t)__shfl_xor((int)mynib, 1);
        if (!(r & 1))
            ((uint8_t*)&hq4[p ^ 1][0])[r >> 1] = (uint8_t)(mynib | (other << 4));
        __syncthreads();                            // ONE barrier per step
        p ^= 1;
    }
}

// ---- K3a: attention scores + softmax + context -> chq = int8 [c | h2] ----
__global__ __launch_bounds__(512) void k_att1(
        const float* __restrict__ fencs, const float* __restrict__ h2s,
        int8_t* __restrict__ chq) {
    __shared__ float h2l[D], sc[NSTEP], red[64];
    __shared__ float ftile[32 * D];
    int s = blockIdx.x, t = threadIdx.x;
    h2l[t] = h2s[(size_t)s * D + t];
    __syncthreads();

    {   // scores[j] = fencs[j] . h2 ; thread (j = t>>2, q = t&3)
        int j = t >> 2, q = t & 3;
        const float4* fr = (const float4*)(fencs + (size_t)j * D + q * 128);
        const float4* hr = (const float4*)(h2l + q * 128);
        float acc = 0.f;
        #pragma unroll 8
        for (int k4 = 0; k4 < 32; k4++) {
            float4 f = fr[k4], hh = hr[k4];
            acc += f.x*hh.x + f.y*hh.y + f.z*hh.z + f.w*hh.w;
        }
        acc += __shfl_xor(acc, 1);
        acc += __shfl_xor(acc, 2);
        if (q == 0) sc[j] = acc;
    }
    __syncthreads();
    if (t < 64) {
        float m = fmaxf(sc[t], sc[t + 64]);
        for (int off = 32; off; off >>= 1) m = fmaxf(m, __shfl_xor(m, off));
        if (t == 0) red[0] = m;
    }
    __syncthreads();
    float mx = red[0];
    __syncthreads();
    if (t < NSTEP) sc[t] = expf(sc[t] - mx);
    __syncthreads();
    if (t < 64) {
        float v = sc[t] + sc[t + 64];
        for (int off = 32; off; off >>= 1) v += __shfl_xor(v, off);
        if (t == 0) red[0] = v;
    }
    __syncthreads();
    float inv = 1.0f / red[0];

    float cacc = 0.f;
    for (int jt = 0; jt < 4; jt++) {
        #pragma unroll
        for (int k = 0; k < 32; k++)
            ftile[t + k * D] = fencs[(size_t)jt * 32 * D + t + k * D];
        __syncthreads();
        #pragma unroll 8
        for (int j = 0; j < 32; j++)
            cacc += sc[jt * 32 + j] * ftile[j * D + t];
        __syncthreads();
    }
    float cv = cacc * inv;
    chq[(size_t)s * 2 * D + t]     = (int8_t)__float2int_rn(cv * 127.f);
    chq[(size_t)s * 2 * D + D + t] = (int8_t)__float2int_rn(h2l[t] * 127.f);
}

// ---- K3b: m = tanh([c,h2] @ Wm^T + bm) as int8 GEMM, 16 blocks ----
__global__ __launch_bounds__(512) void k_att2(
        const int8_t* __restrict__ chq, const int8_t* __restrict__ wmq,
        const float* __restrict__ wmsc, const float* __restrict__ bm,
        int8_t* __restrict__ mq) {
    __shared__ __align__(16) uint32_t a_s[32 * LDA_W];
    __shared__ __align__(16) uint32_t b_s[32 * LDB_W];
    int t = threadIdx.x;
    int v0 = (blockIdx.x & 3) * VTILE;      // col tile
    int r0 = (blockIdx.x >> 2) * 32;        // row tile
    int ti = t >> 5, tj = t & 31;           // ti -> rows r0+2ti..+1 ; tj -> cols v0+4tj..
    int lrow = t >> 3, lq = t & 7;
    int acc[2][4] = {};

    for (int kc = 0; kc < 8; kc++) {        // K = 1024 -> 8 chunks of 128
        if (t < 256) {                      // A: 32 rows x 8 quads
            int row = t >> 3, q = t & 7;
            uint4 av = *(const uint4*)(chq + (size_t)(r0 + row) * 2 * D + kc * 128 + q * 16);
            *(uint4*)&a_s[row * LDA_W + q * 4] = av;
        }
        #pragma unroll
        for (int rep = 0; rep < 2; rep++) { // B: 128 cols x 8 quads
            int row = lrow + rep * 64;
            int v = v0 + row;
            uint4 bv = *(const uint4*)(wmq + (size_t)v * 2 * D + kc * 128 + lq * 16);
            b_s[(lq*4+0) * LDB_W + row] = bv.x;
            b_s[(lq*4+1) * LDB_W + row] = bv.y;
            b_s[(lq*4+2) * LDB_W + row] = bv.z;
            b_s[(lq*4+3) * LDB_W + row] = bv.w;
        }
        __syncthreads();
        #pragma unroll
        for (int q = 0; q < 8; q++) {
            uint4 aw0 = *(const uint4*)&a_s[(ti*2 + 0) * LDA_W + q*4];
            uint4 aw1 = *(const uint4*)&a_s[(ti*2 + 1) * LDA_W + q*4];
            #pragma unroll
            for (int k4 = 0; k4 < 4; k4++) {
                uint4 bw = *(const uint4*)&b_s[(q*4 + k4) * LDB_W + tj * 4];
                uint32_t a0 = (k4 == 0) ? aw0.x : (k4 == 1) ? aw0.y
                            : (k4 == 2) ? aw0.z : aw0.w;
                uint32_t a1 = (k4 == 0) ? aw1.x : (k4 == 1) ? aw1.y
                            : (k4 == 2) ? aw1.z : aw1.w;
                acc[0][0] = sdot4((int)a0, (int)bw.x, acc[0][0]);
                acc[0][1] = sdot4((int)a0, (int)bw.y, acc[0][1]);
                acc[0][2] = sdot4((int)a0, (int)bw.z, acc[0][2]);
                acc[0][3] = sdot4((int)a0, (int)bw.w, acc[0][3]);
                acc[1][0] = sdot4((int)a1, (int)bw.x, acc[1][0]);
                acc[1][1] = sdot4((int)a1, (int)bw.y, acc[1][1]);
                acc[1][2] = sdot4((int)a1, (int)bw.z, acc[1][2]);
                acc[1][3] = sdot4((int)a1, (int)bw.w, acc[1][3]);
            }
        }
        __syncthreads();
    }

    float sw4[4], bm4[4];
    #pragma unroll
    for (int jj = 0; jj < 4; jj++) {
        int col = v0 + tj * 4 + jj;
        sw4[jj] = wmsc[col] * (1.f / (127.f * 127.f));
        bm4[jj] = bm[col];
    }
    #pragma unroll
    for (int i = 0; i < 2; i++) {
        int s = r0 + ti * 2 + i;
        float m0 = tanhf((float)acc[i][0] * sw4[0] + bm4[0]);
        float m1 = tanhf((float)acc[i][1] * sw4[1] + bm4[1]);
        float m2 = tanhf((float)acc[i][2] * sw4[2] + bm4[2]);
        float m3 = tanhf((float)acc[i][3] * sw4[3] + bm4[3]);
        ((uint32_t*)mq)[(size_t)s * (D / 4) + (v0 >> 2) + tj] = pack4(m0, m1, m2, m3, 127.f);
    }
}

// ---- K4: int8 logits GEMM + fused row max/sumexp (r19 verified version) ----
__global__ __launch_bounds__(512) void k_logits(
        const int8_t* __restrict__ mq, const uint32_t* __restrict__ woq2,
        const float* __restrict__ wosc, const float* __restrict__ bo,
        const int* __restrict__ enums,
        float* __restrict__ pmax, float* __restrict__ psum, float* __restrict__ pick) {
    __shared__ __align__(16) uint32_t a_s[128 * LDA_W];
    __shared__ __align__(16) uint32_t b_s[32 * LDB_W];
    int b = blockIdx.x, t = threadIdx.x;
    int v0 = b * VTILE;
    int ti = t >> 5, tj = t & 31;
    int lrow = t >> 3, lq = t & 7;
    int acc[8][4] = {};

    for (int kc = 0; kc < 4; kc++) {
        const uint4* bsrc = (const uint4*)(woq2 + ((size_t)b * 4 + kc) * 4096);
        #pragma unroll
        for (int rep = 0; rep < 2; rep++) {
            int row = lrow + rep * 64;
            uint4 av = *(const uint4*)(mq + (size_t)row * D + kc * 128 + lq * 16);
            *(uint4*)&a_s[row * LDA_W + lq * 4] = av;
            uint4 bv = bsrc[t + rep * 512];
            b_s[(lq*4+0) * LDB_W + row] = bv.x;
            b_s[(lq*4+1) * LDB_W + row] = bv.y;
            b_s[(lq*4+2) * LDB_W + row] = bv.z;
            b_s[(lq*4+3) * LDB_W + row] = bv.w;
        }
        __syncthreads();
        #pragma unroll
        for (int q = 0; q < 8; q++) {
            uint4 aw[8];
            #pragma unroll
            for (int i = 0; i < 8; i++)
                aw[i] = *(const uint4*)&a_s[(ti*8 + i) * LDA_W + q*4];
            #pragma unroll
            for (int k4 = 0; k4 < 4; k4++) {
                uint4 bw = *(const uint4*)&b_s[(q*4 + k4) * LDB_W + tj * 4];
                #pragma unroll
                for (int i = 0; i < 8; i++) {
                    uint32_t a = (k4 == 0) ? aw[i].x : (k4 == 1) ? aw[i].y
                               : (k4 == 2) ? aw[i].z : aw[i].w;
                    acc[i][0] = sdot4((int)a, (int)bw.x, acc[i][0]);
                    acc[i][1] = sdot4((int)a, (int)bw.y, acc[i][1]);
                    acc[i][2] = sdot4((int)a, (int)bw.z, acc[i][2]);
                    acc[i][3] = sdot4((int)a, (int)bw.w, acc[i][3]);
                }
            }
        }
        __syncthreads();
    }

    float sw4[4], bo4[4];
    int vld[4];
    #pragma unroll
    for (int jj = 0; jj < 4; jj++) {
        int v = v0 + tj * 4 + jj;
        vld[jj] = (v < EVOC);
        sw4[jj] = vld[jj] ? wosc[v] * (1.f / 127.f) : 0.f;
        bo4[jj] = vld[jj] ? bo[v] : 0.f;
    }
    #pragma unroll
    for (int i = 0; i < 8; i++) {
        int s = ti * 8 + i;
        float l[4];
        float mx = -1e30f;
        #pragma unroll
        for (int jj = 0; jj < 4; jj++) {
            l[jj] = vld[jj] ? (float)acc[i][jj] * sw4[jj] + bo4[jj] : -1e30f;
            mx = fmaxf(mx, l[jj]);
        }
        #pragma unroll
        for (int off = 1; off < 32; off <<= 1) mx = fmaxf(mx, __shfl_xor(mx, off));
        float sm = 0.f;
        #pragma unroll
        for (int jj = 0; jj < 4; jj++)
            if (vld[jj]) sm += expf(l[jj] - mx);
        #pragma unroll
        for (int off = 1; off < 32; off <<= 1) sm += __shfl_xor(sm, off);
        if (tj == 0) { pmax[b * NSTEP + s] = mx; psum[b * NSTEP + s] = sm; }
        int tgt = enums[s + 1];
        if (tgt >= v0 && tgt < v0 + VTILE) {
            int c = tgt - v0;
            if ((c >> 2) == tj) pick[s] = l[c & 3];
        }
    }
}

// ---- K5a: per-step logsumexp combine, 128 blocks in parallel ----
__global__ __launch_bounds__(256) void k_final_par(
        const float* __restrict__ pmax, const float* __restrict__ psum,
        const float* __restrict__ pick, float* __restrict__ lp) {
    __shared__ float red[8];
    int s = blockIdx.x, t = threadIdx.x;
    float M = -1e30f;
    for (int b = t; b < NBV; b += 256) M = fmaxf(M, pmax[b * NSTEP + s]);
    for (int off = 32; off; off >>= 1) M = fmaxf(M, __shfl_xor(M, off));
    if ((t & 63) == 0) red[t >> 6] = M;
    __syncthreads();
    M = fmaxf(fmaxf(red[0], red[1]), fmaxf(red[2], red[3]));
    float S = 0.f;
    for (int b = t; b < NBV; b += 256) S += psum[b * NSTEP + s] * expf(pmax[b * NSTEP + s] - M);
    for (int off = 32; off; off >>= 1) S += __shfl_xor(S, off);
    if ((t & 63) == 0) red[4 + (t >> 6)] = S;
    __syncthreads();
    if (t == 0) {
        S = red[4] + red[5] + red[6] + red[7];
        lp[s] = pick[s] - (M + logf(S));
    }
}

// ---- K5b: sum 128 logprobs ----
__global__ void k_final_sum(const float* __restrict__ lp, float* __restrict__ out) {
    __shared__ float red[NSTEP];
    int t = threadIdx.x;
    red[t] = lp[t];
    __syncthreads();
    for (int off = 64; off > 0; off >>= 1) {
        if (t < off) red[t] += red[t + off];
        __syncthreads();
    }
    if (t == 0) out[0] = red[0];
}

extern "C" void kernel_launch(void* const* d_in, const int* in_sizes, int n_in,
                              void* d_out, int out_size, void* d_ws, size_t ws_size,
                              hipStream_t stream) {
    const int*   fnums = (const int*)  d_in[0];
    const int*   enums = (const int*)  d_in[1];
    const float* emb_f = (const float*)d_in[2];
    const float* Wih_e = (const float*)d_in[3];
    const float* Whh_e = (const float*)d_in[4];
    const float* b_e   = (const float*)d_in[5];
    const float* h0_e  = (const float*)d_in[6];
    const float* emb_d = (const float*)d_in[7];
    const float* Wih_d = (const float*)d_in[8];
    const float* Whh_d = (const float*)d_in[9];
    const float* b_d   = (const float*)d_in[10];
    const float* h0_d  = (const float*)d_in[11];
    const float* Wm    = (const float*)d_in[12];
    const float* bm    = (const float*)d_in[13];
    const float* Wo    = (const float*)d_in[14];
    const float* bo    = (const float*)d_in[15];

    float* ws = (float*)d_ws;
    float* pre_e = ws;                        // 65536
    float* pre_d = ws + 65536;                // 65536
    float* fencs = ws + 131072;               // 65536
    float* h2s   = ws + 196608;               // 65536
    float* pmax  = ws + 262144;               // 50048
    float* psum  = ws + 312192;               // 50048
    float* pick  = ws + 362240;               // 128
    float* lp    = ws + 362368;               // 128
    float* qsc   = ws + 362496;               // 1024
    float* wmsc  = ws + 363520;               // 512
    float* wosc  = ws + 364032;               // 50048
    uint32_t* q4 = (uint32_t*)(ws + 414080);  // 65536 u32 = 256 KB int4 scan weights
    int8_t*   wmq  = (int8_t*)(ws + 479616);  // 512 KB
    int8_t*   chq  = (int8_t*)(ws + 610688);  // 128 KB
    int8_t*   mq   = (int8_t*)(ws + 643456);  // 64 KB
    uint32_t* woq2 = (uint32_t*)(ws + 659840);// 391*16384 u32 = 25.6 MB (padded)

    k_prep2<<<dim3(512), dim3(256), 0, stream>>>(
        Whh_e, Whh_d, fnums, enums, emb_f, emb_d, Wih_e, Wih_d, b_e, b_d,
        q4, qsc, pre_e, pre_d);
    k_scan_fused<<<dim3(2 + WM8 + WO8), dim3(512), 0, stream>>>(
        q4, qsc, pre_e, pre_d, h0_e, h0_d, fencs, h2s,
        Wm, Wo, wmq, wmsc, woq2, wosc);
    k_att1<<<dim3(NSTEP), dim3(512), 0, stream>>>(fencs, h2s, chq);
    k_att2<<<dim3(16), dim3(512), 0, stream>>>(chq, wmq, wmsc, bm, mq);
    k_logits<<<dim3(NBV), dim3(512), 0, stream>>>(mq, woq2, wosc, bo, enums, pmax, psum, pick);
    k_final_par<<<dim3(NSTEP), dim3(256), 0, stream>>>(pmax, psum, pick, lp);
    k_final_sum<<<dim3(1), dim3(NSTEP), 0, stream>>>(lp, (float*)d_out);
}